// Round 11
// baseline (2876.249 us; speedup 1.0000x reference)
//
#include <hip/hip_runtime.h>
#include <math.h>
#include <stdint.h>

#define NPTS 4096
#define KMAX 300
#define SORT_N 512
#define NTHR 256
#define PERTHR 16            // NPTS / NTHR
#define NFEAT 336            // features kept for ranks < NFEAT
#define TIE_TOL 4u           // full-bits ulp window: "reference order unknowable"
#define NBIN 4096            // stage-1 histogram on bits>>20
#define NRBIN 2048           // relative counting-sort bins on (c12 - minbin)

typedef unsigned long long u64;

// EXACT d2 rounding (matches R7/R10): sequential, no fma, fmax 0.
__device__ __forceinline__ uint32_t d2_bits(float pix, float piy, float piz, float sqi,
                                            const float* __restrict__ ptsB, int j) {
#pragma clang fp contract(off)
    float xj = ptsB[3*j], yj = ptsB[3*j+1], zj = ptsB[3*j+2];
    float sqj = xj*xj + yj*yj + zj*zj;
    float dot = pix*xj + piy*yj + piz*zj;
    float d2 = sqi + sqj - 2.0f*dot;
    d2 = fmaxf(d2, 0.0f);
    return __float_as_uint(d2);          // nonneg float: bits are order-monotone
}

__global__ __launch_bounds__(NTHR) void ppf_kernel(
    const float* __restrict__ pts,
    const float* __restrict__ nrm,
    float* __restrict__ out)
{
    const int row = blockIdx.x;          // b*4096 + i
    const int b = row >> 12;
    const int i = row & (NPTS - 1);
    const int t = threadIdx.x;

    // s_buf (16 KB) phases:
    //  A: uint32 hist[4096]                     (whole buffer)
    //  B: rhist[2048] @0 (8 KB) | key_tmp u64[512] @8K | key_sorted u64[512] @12K
    //  C: feat[336][4] @0 (5.25 KB, over dead rhist)
    __shared__ __align__(16) unsigned char s_buf[NBIN * 4];
    uint32_t* s_hist = (uint32_t*)s_buf;
    uint32_t* s_rhist = (uint32_t*)s_buf;                    // 2048 bins
    u64* s_ktmp = (u64*)(s_buf + 8192);
    u64* s_ksort = (u64*)(s_buf + 12288);
    float (*s_feat)[4] = (float(*)[4])s_buf;
    __shared__ uint32_t s_gsum[NTHR];
    __shared__ uint32_t s_sel;           // stage1: sel1; stage2: 20-bit prefix P
    __shared__ uint32_t s_below;
    __shared__ uint32_t s_minbin;
    __shared__ uint32_t s_M;

    const float* ptsB = pts + (size_t)b * NPTS * 3;
    const float* nrmB = nrm + (size_t)b * NPTS * 3;

    const float pix = ptsB[3*i], piy = ptsB[3*i+1], piz = ptsB[3*i+2];
    const float nix = nrmB[3*i], niy = nrmB[3*i+1], niz = nrmB[3*i+2];
    float sqi;
    {
#pragma clang fp contract(off)
        sqi = pix*pix + piy*piy + piz*piz;
    }

    // ---- A0: zero stage-1 histogram ----
    for (int q = t; q < NBIN; q += NTHR) s_hist[q] = 0;
    __syncthreads();                                          // #1

    // ---- A1: full d2 bits in registers + 12-bit histogram ----
    uint32_t bits[PERTHR];
#pragma unroll
    for (int q = 0; q < PERTHR; ++q) {
        int j = q * NTHR + t;
        bits[q] = d2_bits(pix, piy, piz, sqi, ptsB, j);
        atomicAdd(&s_hist[bits[q] >> 20], 1u);
    }
    __syncthreads();                                          // #2

    // ---- A2: per-thread 16-bin group sums ----
    {
        uint32_t gs = 0;
#pragma unroll
        for (int q = 0; q < 16; ++q) gs += s_hist[t*16 + q];
        s_gsum[t] = gs;
    }
    __syncthreads();                                          // #3

    // ---- A3: t0 scan -> sel1 (bin of rank KMAX), below, minbin ----
    if (t == 0) {
        uint32_t acc = 0, below = 0, selbin = 0, minb = 0xFFFFFFFFu;
        int found = 0;
        for (int g = 0; g < NTHR; ++g) {
            uint32_t gs = s_gsum[g];
            if (minb == 0xFFFFFFFFu && gs > 0) {
                for (int q = 0; q < 16; ++q)
                    if (s_hist[g*16 + q] > 0) { minb = (uint32_t)(g*16 + q); break; }
            }
            if (!found) {
                if (acc + gs >= KMAX) {
                    uint32_t a = acc;
                    for (int q = 0; q < 16; ++q) {
                        uint32_t c = s_hist[g*16 + q];
                        if (a + c >= KMAX) { selbin = (uint32_t)(g*16 + q); below = a; break; }
                        a += c;
                    }
                    found = 1;
                } else acc += gs;
            }
            if (found && minb != 0xFFFFFFFFu) break;
        }
        s_sel = selbin;
        s_below = below;
        s_minbin = minb;
    }
    __syncthreads();                                          // #4
    const uint32_t sel1 = s_sel;
    const uint32_t cmin = s_minbin;

    // ---- A4 prep: zero s_gsum (stage-2 hist), zero rhist, pad key buffers ----
    s_gsum[t] = 0;
    for (int q = t; q < NRBIN; q += NTHR) s_rhist[q] = 0;
    {
        u64* K = s_ktmp;                 // pad both key buffers (1024 u64) to ~0
        for (int q = t; q < 2*SORT_N; q += NTHR) K[q] = ~0ull;
    }
    __syncthreads();                                          // #5

    // ---- A4: stage-2 hist (256 bins on bits[19:12], restricted to bin sel1) ----
#pragma unroll
    for (int q = 0; q < PERTHR; ++q) {
        if ((bits[q] >> 20) == sel1)
            atomicAdd(&s_gsum[(bits[q] >> 12) & 255u], 1u);
    }
    __syncthreads();                                          // #6

    // ---- A5: t0 scan -> exact 20-bit prefix P of rank-KMAX element ----
    if (t == 0) {
        uint32_t k2 = KMAX - s_below;       // >= 1
        uint32_t a = 0, s2 = 0;
        for (int q2 = 0; q2 < 256; ++q2) {
            uint32_t c = s_gsum[q2];
            if (a + c >= k2) { s2 = (uint32_t)q2; break; }
            a += c;
        }
        s_sel = (sel1 << 8) | s2;
    }
    __syncthreads();                                          // #7
    const uint32_t P = s_sel;

    // ---- B1: histogram collected elements on relative 12-bit code ----
#pragma unroll
    for (int q = 0; q < PERTHR; ++q) {
        if ((bits[q] >> 12) <= P + 1) {
            uint32_t rb = (bits[q] >> 20) - cmin;
            if (rb > NRBIN - 1) rb = NRBIN - 1;               // clamp stays exact (bigger group)
            atomicAdd(&s_rhist[rb], 1u);
        }
    }
    __syncthreads();                                          // #8

    // ---- B2: exclusive prefix over 2048 bins (8/thread + t0 scan) ----
    {
        uint32_t gs = 0;
#pragma unroll
        for (int q = 0; q < 8; ++q) gs += s_rhist[t*8 + q];
        s_gsum[t] = gs;
    }
    __syncthreads();                                          // #9
    if (t == 0) {
        uint32_t run = 0;
        for (int g = 0; g < NTHR; ++g) { uint32_t v = s_gsum[g]; s_gsum[g] = run; run += v; }
        s_M = run;
    }
    __syncthreads();                                          // #10
    {
        uint32_t run = s_gsum[t];
#pragma unroll
        for (int q = 0; q < 8; ++q) {
            uint32_t c = s_rhist[t*8 + q];
            s_rhist[t*8 + q] = run;
            run += c;
        }
    }
    __syncthreads();                                          // #11

    // ---- B3: cursor-claim scatter into code groups ----
    uint32_t slotq[PERTHR];
#pragma unroll
    for (int q = 0; q < PERTHR; ++q) {
        slotq[q] = 0xFFFFFFFFu;
        if ((bits[q] >> 12) <= P + 1) {
            uint32_t rb = (bits[q] >> 20) - cmin;
            if (rb > NRBIN - 1) rb = NRBIN - 1;
            uint32_t s = atomicAdd(&s_rhist[rb], 1u);
            slotq[q] = s;
            if (s < SORT_N) {
                int j = q * NTHR + t;
                s_ktmp[s] = ((u64)bits[q] << 32) | (uint32_t)j;
            }
        }
    }
    __syncthreads();                                          // #12

    // ---- B4: exact rank via own-group walk; scatter to key_sorted ----
#pragma unroll
    for (int q = 0; q < PERTHR; ++q) {
        uint32_t s = slotq[q];
        if (s < SORT_N) {
            int j = q * NTHR + t;
            u64 mykey = ((u64)bits[q] << 32) | (uint32_t)j;
            u64 myc = (u64)(bits[q] >> 20);                   // group id (clamped groups share walk)
            uint32_t rbme = (bits[q] >> 20) - cmin; if (rbme > NRBIN-1) rbme = NRBIN-1;
            int cnt = 0;
            int g0 = (int)s;
            while (g0 > 0) {
                u64 kk = s_ktmp[g0 - 1];
                uint32_t rbk = (uint32_t)(kk >> 52) - cmin; if (rbk > NRBIN-1) rbk = NRBIN-1;
                if (rbk != rbme) break;
                cnt += (kk < mykey);
                --g0;
            }
            int gr = (int)s + 1;
            while (gr < SORT_N) {
                u64 kk = s_ktmp[gr];
                if (kk == ~0ull) break;
                uint32_t rbk = (uint32_t)(kk >> 52) - cmin; if (rbk > NRBIN-1) rbk = NRBIN-1;
                if (rbk != rbme) break;
                cnt += (kk < mykey);
                ++gr;
            }
            uint32_t rank = (uint32_t)g0 + (uint32_t)cnt;
            if (rank < SORT_N) s_ksort[rank] = mykey;
            (void)myc;
        }
    }
    __syncthreads();                                          // #13
    const int M = (int)((s_M < (uint32_t)SORT_N) ? s_M : (uint32_t)SORT_N);
    const int T = (M < NFEAT) ? M : NFEAT;

    // ---- C1: PPF features dense by rank (thread t -> ranks t, t+256) ----
    const float inv_pi = 0.31830988618379067154f;
#pragma unroll
    for (int e = 0; e < 2; ++e) {
        int r = t + e * NTHR;
        if (r < T) {
            u64 kk = s_ksort[r];
            if (kk != ~0ull) {
                int j = (int)(uint32_t)(kk & 0xFFFFFFFFull);
                float xj = ptsB[3*j], yj = ptsB[3*j+1], zj = ptsB[3*j+2];
                float mx = nrmB[3*j], my = nrmB[3*j+1], mz = nrmB[3*j+2];
                float dx = xj - pix, dy = yj - piy, dz = zj - piz;
                float d = sqrtf(dx*dx + dy*dy + dz*dz);

                float y1 = nix*dx + niy*dy + niz*dz;
                float c1x = niy*dz - niz*dy, c1y = niz*dx - nix*dz, c1z = nix*dy - niy*dx;
                float x1 = sqrtf(c1x*c1x + c1y*c1y + c1z*c1z);
                float a1 = atan2f(x1, y1) * inv_pi;

                float y2 = mx*dx + my*dy + mz*dz;
                float c2x = my*dz - mz*dy, c2y = mz*dx - mx*dz, c2z = mx*dy - my*dx;
                float x2 = sqrtf(c2x*c2x + c2y*c2y + c2z*c2z);
                float a2 = atan2f(x2, y2) * inv_pi;

                float y3 = nix*mx + niy*my + niz*mz;
                float c3x = niy*mz - niz*my, c3y = niz*mx - nix*mz, c3z = nix*my - niy*mx;
                float x3 = sqrtf(c3x*c3x + c3y*c3y + c3z*c3z);
                float a3 = atan2f(x3, y3) * inv_pi;

                // self-point: reference reductions init accumulator with +0.0 ->
                // y = +0 regardless of signed-zero products -> arctan2(+0,+0)=0.
                if (j == i) { d = 0.0f; a1 = 0.0f; a2 = 0.0f; }

                s_feat[r][0] = d; s_feat[r][1] = a1; s_feat[r][2] = a2; s_feat[r][3] = a3;
            }
        }
    }
    __syncthreads();                                          // #14

    // ---- C2: band means with tie-run smoothing at boundaries (identical to R10) ----
    if (t < 24) {
        const int band = t >> 2, f = t & 3;
        const int lo = (band == 0) ? 0 : (10 << (band - 1));
        const int hi = (band == 5) ? 300 : (10 << band);

        float sum = 0.f;
        int mid_lo = lo;
        int mid_hi = (hi < T) ? hi : T;

        #define BITS(r) ((uint32_t)(s_ksort[(r)] >> 32))
        #define CHAINED(r) (BITS(r) - BITS((r)-1) <= TIE_TOL)

        if (lo > 0 && lo < T && CHAINED(lo)) {
            int a = lo - 1; while (a > 0 && CHAINED(a)) --a;
            int bq = lo;    while (bq + 1 < T && CHAINED(bq + 1)) ++bq;
            float w = (float)(bq + 1 - lo) / (float)(bq + 1 - a);
            for (int r = a; r <= bq; ++r) sum += w * s_feat[r][f];
            mid_lo = bq + 1;
        }
        if (hi < T && CHAINED(hi)) {
            int a = hi - 1; while (a > 0 && CHAINED(a)) --a;
            int bq = hi;    while (bq + 1 < T && CHAINED(bq + 1)) ++bq;
            float w = (float)(hi - a) / (float)(bq + 1 - a);
            for (int r = a; r <= bq; ++r) sum += w * s_feat[r][f];
            mid_hi = a;
        }
        #undef BITS
        #undef CHAINED

        for (int r = mid_lo; r < mid_hi; ++r) sum += s_feat[r][f];
        out[(size_t)row * 24 + band * 4 + f] = sum / (float)(hi - lo);
    }
}

extern "C" void kernel_launch(void* const* d_in, const int* in_sizes, int n_in,
                              void* d_out, int out_size, void* d_ws, size_t ws_size,
                              hipStream_t stream) {
    (void)n_in; (void)out_size; (void)d_ws; (void)ws_size;
    const float* pts = (const float*)d_in[0];
    const float* nrm = (const float*)d_in[1];
    float* out = (float*)d_out;
    const int rows = in_sizes[0] / 3;   // b * n = 32768
    ppf_kernel<<<dim3(rows), dim3(NTHR), 0, stream>>>(pts, nrm, out);
}

// Round 12
// 1070.927 us; speedup vs baseline: 2.6858x; 2.6858x over previous
//
#include <hip/hip_runtime.h>
#include <math.h>
#include <stdint.h>

#define NPTS 4096
#define KMAX 300
#define SORT_N 512
#define NTHR 256
#define PERTHR 16            // NPTS / NTHR
#define NFEAT 336            // features kept for ranks < NFEAT
#define TIE_TOL 4u           // full-bits ulp window: "reference order unknowable"
#define NBIN 4096            // stage-1 histogram on bits>>20
#define NSEG 256             // relative segment bins (clamped)

typedef unsigned long long u64;

// EXACT d2 rounding (matches R7/R10): sequential, no fma, fmax 0.
__device__ __forceinline__ uint32_t d2_bits(float pix, float piy, float piz, float sqi,
                                            const float* __restrict__ ptsB, int j) {
#pragma clang fp contract(off)
    float xj = ptsB[3*j], yj = ptsB[3*j+1], zj = ptsB[3*j+2];
    float sqj = xj*xj + yj*yj + zj*zj;
    float dot = pix*xj + piy*yj + piz*zj;
    float d2 = sqi + sqj - 2.0f*dot;
    d2 = fmaxf(d2, 0.0f);
    return __float_as_uint(d2);          // nonneg float: bits are order-monotone
}

__global__ __launch_bounds__(NTHR) void ppf_kernel(
    const float* __restrict__ pts,
    const float* __restrict__ nrm,
    float* __restrict__ out)
{
    const int row = blockIdx.x;          // b*4096 + i
    const int b = row >> 12;
    const int i = row & (NPTS - 1);
    const int t = threadIdx.x;

    // s_buf (16 KB) phases:
    //  A: uint32 hist[4096] (16 KB)
    //  B/C: ktmp u64[512] @0 | ksort u64[512] @4K | feat[336][4] @8K (5.25 KB)
    __shared__ __align__(16) unsigned char s_buf[NBIN * 4];
    uint32_t* s_hist = (uint32_t*)s_buf;
    u64* s_ktmp = (u64*)s_buf;
    u64* s_ksort = (u64*)(s_buf + 4096);
    float (*s_feat)[4] = (float(*)[4])(s_buf + 8192);
    __shared__ uint32_t s_gsum[NTHR];
    __shared__ uint32_t s_pfx[NSEG + 1];
    __shared__ uint32_t s_cur[NSEG];
    __shared__ uint32_t s_sel;           // stage1: sel1; stage2: 20-bit prefix P
    __shared__ uint32_t s_below;
    __shared__ uint32_t s_minbin;
    __shared__ uint32_t s_M;

    const float* ptsB = pts + (size_t)b * NPTS * 3;
    const float* nrmB = nrm + (size_t)b * NPTS * 3;

    const float pix = ptsB[3*i], piy = ptsB[3*i+1], piz = ptsB[3*i+2];
    const float nix = nrmB[3*i], niy = nrmB[3*i+1], niz = nrmB[3*i+2];
    float sqi;
    {
#pragma clang fp contract(off)
        sqi = pix*pix + piy*piy + piz*piz;
    }

    // ---- A0: zero stage-1 histogram ----
    for (int q = t; q < NBIN; q += NTHR) s_hist[q] = 0;
    __syncthreads();                                          // #1

    // ---- A1: full d2 bits in registers + 12-bit histogram ----
    uint32_t bits[PERTHR];
#pragma unroll
    for (int q = 0; q < PERTHR; ++q) {
        int j = q * NTHR + t;
        bits[q] = d2_bits(pix, piy, piz, sqi, ptsB, j);
        atomicAdd(&s_hist[bits[q] >> 20], 1u);
    }
    __syncthreads();                                          // #2

    // ---- A2: per-thread 16-bin group sums ----
    {
        uint32_t gs = 0;
#pragma unroll
        for (int q = 0; q < 16; ++q) gs += s_hist[t*16 + q];
        s_gsum[t] = gs;
    }
    __syncthreads();                                          // #3

    // ---- A3: t0 scan -> sel1 (bin of rank KMAX), below, minbin (R11-proven) ----
    if (t == 0) {
        uint32_t acc = 0, below = 0, selbin = 0, minb = 0xFFFFFFFFu;
        int found = 0;
        for (int g = 0; g < NTHR; ++g) {
            uint32_t gs = s_gsum[g];
            if (minb == 0xFFFFFFFFu && gs > 0) {
                for (int q = 0; q < 16; ++q)
                    if (s_hist[g*16 + q] > 0) { minb = (uint32_t)(g*16 + q); break; }
            }
            if (!found) {
                if (acc + gs >= KMAX) {
                    uint32_t a = acc;
                    for (int q = 0; q < 16; ++q) {
                        uint32_t c = s_hist[g*16 + q];
                        if (a + c >= KMAX) { selbin = (uint32_t)(g*16 + q); below = a; break; }
                        a += c;
                    }
                    found = 1;
                } else acc += gs;
            }
            if (found && minb != 0xFFFFFFFFu) break;
        }
        s_sel = selbin;
        s_below = below;
        s_minbin = minb;
    }
    __syncthreads();                                          // #4
    const uint32_t sel1 = s_sel;
    const uint32_t cmin = s_minbin;

    // ---- A4 prep: zero stage-2 hist and segment counters ----
    s_gsum[t] = 0;
    s_pfx[t] = 0;
    if (t == 0) s_pfx[NSEG] = 0;
    __syncthreads();                                          // #5

    // ---- A4: stage-2 hist (256 bins on bits[19:12], restricted to bin sel1) ----
#pragma unroll
    for (int q = 0; q < PERTHR; ++q) {
        if ((bits[q] >> 20) == sel1)
            atomicAdd(&s_gsum[(bits[q] >> 12) & 255u], 1u);
    }
    __syncthreads();                                          // #6

    // ---- A5: t0 scan -> exact 20-bit prefix P of rank-KMAX element ----
    if (t == 0) {
        uint32_t k2 = KMAX - s_below;       // >= 1
        uint32_t a = 0, s2 = 0;
        for (int q2 = 0; q2 < 256; ++q2) {
            uint32_t c = s_gsum[q2];
            if (a + c >= k2) { s2 = (uint32_t)q2; break; }
            a += c;
        }
        s_sel = (sel1 << 8) | s2;
    }
    __syncthreads();                                          // #7
    const uint32_t P = s_sel;

    // ---- B1: count collected elements per relative segment ----
#pragma unroll
    for (int q = 0; q < PERTHR; ++q) {
        if ((bits[q] >> 12) <= P + 1) {
            uint32_t rb = (bits[q] >> 20) - cmin;
            if (rb > NSEG - 1) rb = NSEG - 1;                 // clamp: merged segment stays exact
            atomicAdd(&s_pfx[rb], 1u);
        }
    }
    __syncthreads();                                          // #8

    // ---- B2: t0 exclusive prefix (pfx) + cursor copy ----
    if (t == 0) {
        uint32_t run = 0;
        for (int q = 0; q < NSEG; ++q) {
            uint32_t c = s_pfx[q];
            s_pfx[q] = run;
            s_cur[q] = run;
            run += c;
        }
        s_pfx[NSEG] = run;
        s_M = run;
    }
    __syncthreads();                                          // #9

    // ---- B3: cursor-claim scatter into contiguous segments ----
#pragma unroll
    for (int q = 0; q < PERTHR; ++q) {
        if ((bits[q] >> 12) <= P + 1) {
            uint32_t rb = (bits[q] >> 20) - cmin;
            if (rb > NSEG - 1) rb = NSEG - 1;
            uint32_t s = atomicAdd(&s_cur[rb], 1u);
            if (s < SORT_N) {
                int j = q * NTHR + t;
                s_ktmp[s] = ((u64)bits[q] << 32) | (uint32_t)j;
            }
        }
    }
    __syncthreads();                                          // #10
    const int M = (int)((s_M < (uint32_t)SORT_N) ? s_M : (uint32_t)SORT_N);
    const int T = (M < NFEAT) ? M : NFEAT;

    // ---- B4: rank within own segment (dense independent reads), scatter sorted ----
    u64 mykey[2]; int myrank[2];
#pragma unroll
    for (int e = 0; e < 2; ++e) {
        int s = t + e * NTHR;
        mykey[e] = ~0ull; myrank[e] = -1;
        if (s < M) {
            u64 kk = s_ktmp[s];
            uint32_t b32 = (uint32_t)(kk >> 32);
            uint32_t rb = (b32 >> 20) - cmin;
            if (rb > NSEG - 1) rb = NSEG - 1;
            int lo = (int)s_pfx[rb];
            int hi = (int)s_pfx[rb + 1];
            if (hi > M) hi = M;
            int cnt = 0;
            for (int r = lo; r < hi; ++r)
                cnt += (s_ktmp[r] < kk);
            mykey[e] = kk;
            myrank[e] = lo + cnt;
        }
    }
    __syncthreads();                                          // #11 (ktmp reads done)
#pragma unroll
    for (int e = 0; e < 2; ++e)
        if (myrank[e] >= 0 && myrank[e] < SORT_N) s_ksort[myrank[e]] = mykey[e];
    __syncthreads();                                          // #12

    // ---- C1: PPF features dense by rank (thread t -> ranks t, t+256) ----
    const float inv_pi = 0.31830988618379067154f;
#pragma unroll
    for (int e = 0; e < 2; ++e) {
        int r = t + e * NTHR;
        if (r < T) {
            u64 kk = s_ksort[r];
            int j = (int)(uint32_t)(kk & 0xFFFFFFFFull);
            float xj = ptsB[3*j], yj = ptsB[3*j+1], zj = ptsB[3*j+2];
            float mx = nrmB[3*j], my = nrmB[3*j+1], mz = nrmB[3*j+2];
            float dx = xj - pix, dy = yj - piy, dz = zj - piz;
            float d = sqrtf(dx*dx + dy*dy + dz*dz);

            float y1 = nix*dx + niy*dy + niz*dz;
            float c1x = niy*dz - niz*dy, c1y = niz*dx - nix*dz, c1z = nix*dy - niy*dx;
            float x1 = sqrtf(c1x*c1x + c1y*c1y + c1z*c1z);
            float a1 = atan2f(x1, y1) * inv_pi;

            float y2 = mx*dx + my*dy + mz*dz;
            float c2x = my*dz - mz*dy, c2y = mz*dx - mx*dz, c2z = mx*dy - my*dx;
            float x2 = sqrtf(c2x*c2x + c2y*c2y + c2z*c2z);
            float a2 = atan2f(x2, y2) * inv_pi;

            float y3 = nix*mx + niy*my + niz*mz;
            float c3x = niy*mz - niz*my, c3y = niz*mx - nix*mz, c3z = nix*my - niy*mx;
            float x3 = sqrtf(c3x*c3x + c3y*c3y + c3z*c3z);
            float a3 = atan2f(x3, y3) * inv_pi;

            // self-point: reference reductions init accumulator with +0.0 ->
            // y = +0 regardless of signed-zero products -> arctan2(+0,+0)=0.
            if (j == i) { d = 0.0f; a1 = 0.0f; a2 = 0.0f; }

            s_feat[r][0] = d; s_feat[r][1] = a1; s_feat[r][2] = a2; s_feat[r][3] = a3;
        }
    }
    __syncthreads();                                          // #13

    // ---- C2: band means with tie-run smoothing at boundaries (identical to R10) ----
    if (t < 24) {
        const int band = t >> 2, f = t & 3;
        const int lo = (band == 0) ? 0 : (10 << (band - 1));
        const int hi = (band == 5) ? 300 : (10 << band);

        float sum = 0.f;
        int mid_lo = lo;
        int mid_hi = (hi < T) ? hi : T;

        #define BITS(r) ((uint32_t)(s_ksort[(r)] >> 32))
        #define CHAINED(r) (BITS(r) - BITS((r)-1) <= TIE_TOL)

        if (lo > 0 && lo < T && CHAINED(lo)) {
            int a = lo - 1; while (a > 0 && CHAINED(a)) --a;
            int bq = lo;    while (bq + 1 < T && CHAINED(bq + 1)) ++bq;
            float w = (float)(bq + 1 - lo) / (float)(bq + 1 - a);
            for (int r = a; r <= bq; ++r) sum += w * s_feat[r][f];
            mid_lo = bq + 1;
        }
        if (hi < T && CHAINED(hi)) {
            int a = hi - 1; while (a > 0 && CHAINED(a)) --a;
            int bq = hi;    while (bq + 1 < T && CHAINED(bq + 1)) ++bq;
            float w = (float)(hi - a) / (float)(bq + 1 - a);
            for (int r = a; r <= bq; ++r) sum += w * s_feat[r][f];
            mid_hi = a;
        }
        #undef BITS
        #undef CHAINED

        for (int r = mid_lo; r < mid_hi; ++r) sum += s_feat[r][f];
        out[(size_t)row * 24 + band * 4 + f] = sum / (float)(hi - lo);
    }
}

extern "C" void kernel_launch(void* const* d_in, const int* in_sizes, int n_in,
                              void* d_out, int out_size, void* d_ws, size_t ws_size,
                              hipStream_t stream) {
    (void)n_in; (void)out_size; (void)d_ws; (void)ws_size;
    const float* pts = (const float*)d_in[0];
    const float* nrm = (const float*)d_in[1];
    float* out = (float*)d_out;
    const int rows = in_sizes[0] / 3;   // b * n = 32768
    ppf_kernel<<<dim3(rows), dim3(NTHR), 0, stream>>>(pts, nrm, out);
}

// Round 13
// 553.512 us; speedup vs baseline: 5.1964x; 1.9348x over previous
//
#include <hip/hip_runtime.h>
#include <math.h>
#include <stdint.h>

#define NPTS 4096
#define KMAX 300
#define SORT_N 512
#define NTHR 256
#define PERTHR 16            // NPTS / NTHR
#define NFEAT 336            // features kept for ranks < NFEAT
#define TIE_TOL 4u           // full-bits ulp window: "reference order unknowable"
#define NBIN 4096            // stage-1 histogram on bits>>20
#define NBKT 64              // rank buckets anchored at the cut

typedef unsigned long long u64;

// EXACT d2 rounding (matches R7/R10): sequential, no fma, fmax 0.
__device__ __forceinline__ uint32_t d2_bits(float pix, float piy, float piz, float sqi,
                                            const float* __restrict__ ptsB, int j) {
#pragma clang fp contract(off)
    float xj = ptsB[3*j], yj = ptsB[3*j+1], zj = ptsB[3*j+2];
    float sqj = xj*xj + yj*yj + zj*zj;
    float dot = pix*xj + piy*yj + piz*zj;
    float d2 = sqi + sqj - 2.0f*dot;
    d2 = fmaxf(d2, 0.0f);
    return __float_as_uint(d2);          // nonneg float: bits are order-monotone
}

__device__ __forceinline__ uint32_t bucket_of(uint32_t code12, uint32_t sel1) {
    uint32_t d = (code12 >= sel1) ? 0u : (sel1 - code12);
    if (d > NBKT - 1) d = NBKT - 1;
    return (uint32_t)(NBKT - 1) - d;     // monotone nondecreasing in code12
}

__global__ __launch_bounds__(NTHR) void ppf_kernel(
    const float* __restrict__ pts,
    const float* __restrict__ nrm,
    float* __restrict__ out)
{
    const int row = blockIdx.x;          // b*4096 + i
    const int b = row >> 12;
    const int i = row & (NPTS - 1);
    const int t = threadIdx.x;

    // s_buf (16 KB) phases:
    //  A: uint32 hist[4096] (16 KB)
    //  B/C: ktmp u64[512] @0 | ksort u64[512] @4K | feat[336][4] @8K (5.25 KB)
    __shared__ __align__(16) unsigned char s_buf[NBIN * 4];
    uint32_t* s_hist = (uint32_t*)s_buf;
    u64* s_ktmp = (u64*)s_buf;
    u64* s_ksort = (u64*)(s_buf + 4096);
    float (*s_feat)[4] = (float(*)[4])(s_buf + 8192);
    __shared__ uint32_t s_gsum[NTHR];    // stage-1 group sums, then stage-2 hist
    __shared__ uint32_t s_bcnt[NBKT];
    __shared__ uint32_t s_pfx[NBKT];
    __shared__ uint32_t s_cur[NBKT];
    __shared__ uint32_t s_sel;           // stage1: sel1; stage2: 20-bit prefix P
    __shared__ uint32_t s_below;
    __shared__ uint32_t s_M;

    const float* ptsB = pts + (size_t)b * NPTS * 3;
    const float* nrmB = nrm + (size_t)b * NPTS * 3;

    const float pix = ptsB[3*i], piy = ptsB[3*i+1], piz = ptsB[3*i+2];
    const float nix = nrmB[3*i], niy = nrmB[3*i+1], niz = nrmB[3*i+2];
    float sqi;
    {
#pragma clang fp contract(off)
        sqi = pix*pix + piy*piy + piz*piz;
    }

    // ---- A0: zero stage-1 histogram (vectorized) ----
    {
        uint4* H4 = (uint4*)s_hist;
#pragma unroll
        for (int q = 0; q < 4; ++q) H4[q * NTHR + t] = make_uint4(0u, 0u, 0u, 0u);
    }
    __syncthreads();                                          // #1

    // ---- A1: full d2 bits in registers + 12-bit histogram ----
    uint32_t bits[PERTHR];
#pragma unroll
    for (int q = 0; q < PERTHR; ++q) {
        int j = q * NTHR + t;
        bits[q] = d2_bits(pix, piy, piz, sqi, ptsB, j);
        atomicAdd(&s_hist[bits[q] >> 20], 1u);
    }
    __syncthreads();                                          // #2

    // ---- A2: per-thread 16-bin group sums ----
    {
        uint32_t gs = 0;
#pragma unroll
        for (int q = 0; q < 16; ++q) gs += s_hist[t*16 + q];
        s_gsum[t] = gs;
    }
    __syncthreads();                                          // #3

    // ---- A3: t0 scan -> sel1 (bin of rank KMAX) + below (R10-proven, early exit) ----
    if (t == 0) {
        uint32_t acc = 0, below = 0, selbin = 0;
        int found = 0;
        for (int g = 0; g < NTHR && !found; ++g) {
            uint32_t gs = s_gsum[g];
            if (acc + gs >= KMAX) {
                uint32_t a = acc;
                for (int q = 0; q < 16; ++q) {
                    uint32_t c = s_hist[g*16 + q];
                    if (a + c >= KMAX) { selbin = (uint32_t)(g*16 + q); below = a; break; }
                    a += c;
                }
                found = 1;
            } else acc += gs;
        }
        s_sel = selbin;
        s_below = below;
    }
    __syncthreads();                                          // #4
    const uint32_t sel1 = s_sel;

    // ---- A4 prep: zero stage-2 hist + bucket counts ----
    s_gsum[t] = 0;
    if (t < NBKT) s_bcnt[t] = 0;
    __syncthreads();                                          // #5

    // ---- A4: stage-2 hist (256 bins on bits[19:12], restricted to bin sel1) ----
#pragma unroll
    for (int q = 0; q < PERTHR; ++q) {
        if ((bits[q] >> 20) == sel1)
            atomicAdd(&s_gsum[(bits[q] >> 12) & 255u], 1u);
    }
    __syncthreads();                                          // #6

    // ---- A5: t0 scan -> exact 20-bit prefix P of rank-KMAX element ----
    if (t == 0) {
        uint32_t k2 = KMAX - s_below;       // >= 1
        uint32_t a = 0, s2 = 0;
        for (int q2 = 0; q2 < 256; ++q2) {
            uint32_t c = s_gsum[q2];
            if (a + c >= k2) { s2 = (uint32_t)q2; break; }
            a += c;
        }
        s_sel = (sel1 << 8) | s2;
    }
    __syncthreads();                                          // #7
    const uint32_t P = s_sel;

    // ---- B1: count candidates per bucket ----
#pragma unroll
    for (int q = 0; q < PERTHR; ++q) {
        if ((bits[q] >> 12) <= P + 1)
            atomicAdd(&s_bcnt[bucket_of(bits[q] >> 20, sel1)], 1u);
    }
    __syncthreads();                                          // #8

    // ---- B2: wave-0 lanes compute 64-bin prefix via broadcast reads (no serial t0) ----
    if (t < NBKT) {
        uint32_t pfx = 0;
#pragma unroll
        for (int q = 0; q < NBKT; ++q) {
            uint32_t c = s_bcnt[q];               // broadcast read (same addr all lanes)
            pfx += (q < t) ? c : 0u;
        }
        s_pfx[t] = pfx;
        s_cur[t] = pfx;
        if (t == NBKT - 1) s_M = pfx + s_bcnt[NBKT - 1];
    }
    __syncthreads();                                          // #9

    // ---- B3: cursor-claim scatter into contiguous buckets ----
#pragma unroll
    for (int q = 0; q < PERTHR; ++q) {
        if ((bits[q] >> 12) <= P + 1) {
            uint32_t bk = bucket_of(bits[q] >> 20, sel1);
            uint32_t s = atomicAdd(&s_cur[bk], 1u);
            if (s < SORT_N) {
                int j = q * NTHR + t;
                s_ktmp[s] = ((u64)bits[q] << 32) | (uint32_t)j;
            }
        }
    }
    __syncthreads();                                          // #10
    const int M = (int)((s_M < (uint32_t)SORT_N) ? s_M : (uint32_t)SORT_N);
    const int T = (M < NFEAT) ? M : NFEAT;

    // ---- B4: rank within own bucket (dense reads over grouped layout) ----
    u64 mykey[2]; int myrank[2];
#pragma unroll
    for (int e = 0; e < 2; ++e) {
        int s = t + e * NTHR;
        mykey[e] = ~0ull; myrank[e] = -1;
        if (s < M) {
            u64 kk = s_ktmp[s];
            uint32_t bk = bucket_of((uint32_t)(kk >> 52), sel1);
            int lo = (int)s_pfx[bk];
            int hi = lo + (int)s_bcnt[bk];
            if (hi > M) hi = M;
            int cnt = 0;
            for (int r = lo; r < hi; ++r)
                cnt += (s_ktmp[r] < kk);
            mykey[e] = kk;
            myrank[e] = lo + cnt;
        }
    }
    __syncthreads();                                          // #11 (ktmp reads done)
#pragma unroll
    for (int e = 0; e < 2; ++e)
        if (myrank[e] >= 0 && myrank[e] < SORT_N) s_ksort[myrank[e]] = mykey[e];
    __syncthreads();                                          // #12

    // ---- C1: PPF features dense by rank (thread t -> ranks t, t+256) ----
    const float inv_pi = 0.31830988618379067154f;
#pragma unroll
    for (int e = 0; e < 2; ++e) {
        int r = t + e * NTHR;
        if (r < T) {
            u64 kk = s_ksort[r];
            int j = (int)(uint32_t)(kk & 0xFFFFFFFFull);
            float xj = ptsB[3*j], yj = ptsB[3*j+1], zj = ptsB[3*j+2];
            float mx = nrmB[3*j], my = nrmB[3*j+1], mz = nrmB[3*j+2];
            float dx = xj - pix, dy = yj - piy, dz = zj - piz;
            float d = sqrtf(dx*dx + dy*dy + dz*dz);

            float y1 = nix*dx + niy*dy + niz*dz;
            float c1x = niy*dz - niz*dy, c1y = niz*dx - nix*dz, c1z = nix*dy - niy*dx;
            float x1 = sqrtf(c1x*c1x + c1y*c1y + c1z*c1z);
            float a1 = atan2f(x1, y1) * inv_pi;

            float y2 = mx*dx + my*dy + mz*dz;
            float c2x = my*dz - mz*dy, c2y = mz*dx - mx*dz, c2z = mx*dy - my*dx;
            float x2 = sqrtf(c2x*c2x + c2y*c2y + c2z*c2z);
            float a2 = atan2f(x2, y2) * inv_pi;

            float y3 = nix*mx + niy*my + niz*mz;
            float c3x = niy*mz - niz*my, c3y = niz*mx - nix*mz, c3z = nix*my - niy*mx;
            float x3 = sqrtf(c3x*c3x + c3y*c3y + c3z*c3z);
            float a3 = atan2f(x3, y3) * inv_pi;

            // self-point: reference reductions init accumulator with +0.0 ->
            // y = +0 regardless of signed-zero products -> arctan2(+0,+0)=0.
            if (j == i) { d = 0.0f; a1 = 0.0f; a2 = 0.0f; }

            s_feat[r][0] = d; s_feat[r][1] = a1; s_feat[r][2] = a2; s_feat[r][3] = a3;
        }
    }
    __syncthreads();                                          // #13

    // ---- C2: band means with tie-run smoothing at boundaries (identical to R10) ----
    if (t < 24) {
        const int band = t >> 2, f = t & 3;
        const int lo = (band == 0) ? 0 : (10 << (band - 1));
        const int hi = (band == 5) ? 300 : (10 << band);

        float sum = 0.f;
        int mid_lo = lo;
        int mid_hi = (hi < T) ? hi : T;

        #define BITS(r) ((uint32_t)(s_ksort[(r)] >> 32))
        #define CHAINED(r) (BITS(r) - BITS((r)-1) <= TIE_TOL)

        if (lo > 0 && lo < T && CHAINED(lo)) {
            int a = lo - 1; while (a > 0 && CHAINED(a)) --a;
            int bq = lo;    while (bq + 1 < T && CHAINED(bq + 1)) ++bq;
            float w = (float)(bq + 1 - lo) / (float)(bq + 1 - a);
            for (int r = a; r <= bq; ++r) sum += w * s_feat[r][f];
            mid_lo = bq + 1;
        }
        if (hi < T && CHAINED(hi)) {
            int a = hi - 1; while (a > 0 && CHAINED(a)) --a;
            int bq = hi;    while (bq + 1 < T && CHAINED(bq + 1)) ++bq;
            float w = (float)(hi - a) / (float)(bq + 1 - a);
            for (int r = a; r <= bq; ++r) sum += w * s_feat[r][f];
            mid_hi = a;
        }
        #undef BITS
        #undef CHAINED

        for (int r = mid_lo; r < mid_hi; ++r) sum += s_feat[r][f];
        out[(size_t)row * 24 + band * 4 + f] = sum / (float)(hi - lo);
    }
}

extern "C" void kernel_launch(void* const* d_in, const int* in_sizes, int n_in,
                              void* d_out, int out_size, void* d_ws, size_t ws_size,
                              hipStream_t stream) {
    (void)n_in; (void)out_size; (void)d_ws; (void)ws_size;
    const float* pts = (const float*)d_in[0];
    const float* nrm = (const float*)d_in[1];
    float* out = (float*)d_out;
    const int rows = in_sizes[0] / 3;   // b * n = 32768
    ppf_kernel<<<dim3(rows), dim3(NTHR), 0, stream>>>(pts, nrm, out);
}

// Round 14
// 344.967 us; speedup vs baseline: 8.3378x; 1.6045x over previous
//
#include <hip/hip_runtime.h>
#include <math.h>
#include <stdint.h>

#define NPTS 4096
#define KMAX 300
#define SORT_N 512
#define NTHR 256
#define PERTHR 16            // NPTS / NTHR
#define NFEAT 336            // features kept for ranks < NFEAT
#define TIE_TOL 4u           // full-bits ulp window: "reference order unknowable"
#define NBIN 4096            // stage-1 histogram on bits>>20
#define NBKT 64              // rank buckets anchored at the cut

typedef unsigned long long u64;

// EXACT d2 rounding (matches R7/R10/R13): sequential, no fma, fmax 0.
__device__ __forceinline__ uint32_t d2_bits(float pix, float piy, float piz, float sqi,
                                            const float* __restrict__ ptsB, int j) {
#pragma clang fp contract(off)
    float xj = ptsB[3*j], yj = ptsB[3*j+1], zj = ptsB[3*j+2];
    float sqj = xj*xj + yj*yj + zj*zj;
    float dot = pix*xj + piy*yj + piz*zj;
    float d2 = sqi + sqj - 2.0f*dot;
    d2 = fmaxf(d2, 0.0f);
    return __float_as_uint(d2);          // nonneg float: bits are order-monotone
}

__device__ __forceinline__ uint32_t bucket_of(uint32_t code12, uint32_t sel1) {
    uint32_t d = (code12 >= sel1) ? 0u : (sel1 - code12);
    if (d > NBKT - 1) d = NBKT - 1;
    return (uint32_t)(NBKT - 1) - d;     // monotone nondecreasing in code12
}

__global__ __launch_bounds__(NTHR) void ppf_kernel(
    const float* __restrict__ pts,
    const float* __restrict__ nrm,
    float* __restrict__ out)
{
    const int row = blockIdx.x;          // b*4096 + i
    const int b = row >> 12;
    const int i = row & (NPTS - 1);
    const int t = threadIdx.x;

    // s_buf (16 KB) phases:
    //  A: uint32 hist[4096] (16 KB)
    //  B/C: ktmp u64[512] @0 | ksort u64[512] @4K | feat[336][4] @8K (5.25 KB)
    __shared__ __align__(16) unsigned char s_buf[NBIN * 4];
    uint32_t* s_hist = (uint32_t*)s_buf;
    u64* s_ktmp = (u64*)s_buf;
    u64* s_ksort = (u64*)(s_buf + 4096);
    float (*s_feat)[4] = (float(*)[4])(s_buf + 8192);
    __shared__ uint32_t s_gsum[NTHR];    // stage-1 16-bin group sums
    __shared__ uint32_t s_h2[NTHR];      // stage-2 256-bin hist
    __shared__ uint32_t s_s4[64];        // wave-0 4-group partial sums
    __shared__ uint32_t s_bcnt[NBKT];
    __shared__ uint32_t s_pfx[NBKT];
    __shared__ uint32_t s_cur[NBKT];
    __shared__ uint32_t s_sel;           // stage1: sel1; stage2: 20-bit prefix P
    __shared__ uint32_t s_below;
    __shared__ uint32_t s_M;

    const float* ptsB = pts + (size_t)b * NPTS * 3;
    const float* nrmB = nrm + (size_t)b * NPTS * 3;

    const float pix = ptsB[3*i], piy = ptsB[3*i+1], piz = ptsB[3*i+2];
    const float nix = nrmB[3*i], niy = nrmB[3*i+1], niz = nrmB[3*i+2];
    float sqi;
    {
#pragma clang fp contract(off)
        sqi = pix*pix + piy*piy + piz*piz;
    }

    // ---- A0: zero stage-1 histogram (vectorized) ----
    {
        uint4* H4 = (uint4*)s_hist;
#pragma unroll
        for (int q = 0; q < 4; ++q) H4[q * NTHR + t] = make_uint4(0u, 0u, 0u, 0u);
    }
    __syncthreads();                                          // #1

    // ---- A1: full d2 bits in registers + 12-bit histogram ----
    uint32_t bits[PERTHR];
#pragma unroll
    for (int q = 0; q < PERTHR; ++q) {
        int j = q * NTHR + t;
        bits[q] = d2_bits(pix, piy, piz, sqi, ptsB, j);
        atomicAdd(&s_hist[bits[q] >> 20], 1u);
    }
    __syncthreads();                                          // #2

    // ---- A2: per-thread 16-bin group sums; zero stage-2 hist + bucket counts ----
    {
        uint32_t gs = 0;
#pragma unroll
        for (int q = 0; q < 16; ++q) gs += s_hist[t*16 + q];
        s_gsum[t] = gs;
    }
    s_h2[t] = 0;
    if (t < NBKT) s_bcnt[t] = 0;
    __syncthreads();                                          // #3

    // ---- A3 (wave 0, no serial t0): lane l sums 4 groups; in-wave broadcast prefix;
    //      cut-owning lane refines to sel1/below ----
    if (t < 64) {
        uint32_t s4 = s_gsum[4*t] + s_gsum[4*t+1] + s_gsum[4*t+2] + s_gsum[4*t+3];
        s_s4[t] = s4;
        uint32_t pfx = 0;
#pragma unroll
        for (int q = 0; q < 64; ++q) {
            uint32_t c = s_s4[q];                 // broadcast read, in-wave ordered
            pfx += (q < t) ? c : 0u;
        }
        if (pfx < KMAX && pfx + s4 >= KMAX) {     // exactly one lane
            uint32_t a = pfx, selbin = 0, below = 0;
            for (int g = 4*t; g < 4*t + 4; ++g) {
                uint32_t gs = s_gsum[g];
                if (a + gs >= KMAX) {
                    for (int q = 0; q < 16; ++q) {
                        uint32_t c = s_hist[g*16 + q];
                        if (a + c >= KMAX) { selbin = (uint32_t)(g*16 + q); below = a; break; }
                        a += c;
                    }
                    break;
                }
                a += gs;
            }
            s_sel = selbin;
            s_below = below;
        }
    }
    __syncthreads();                                          // #4
    const uint32_t sel1 = s_sel;

    // ---- A4: stage-2 hist (256 bins on bits[19:12], restricted to bin sel1) ----
#pragma unroll
    for (int q = 0; q < PERTHR; ++q) {
        if ((bits[q] >> 20) == sel1)
            atomicAdd(&s_h2[(bits[q] >> 12) & 255u], 1u);
    }
    __syncthreads();                                          // #5

    // ---- A5 (wave 0): parallel scan of 256-bin stage-2 hist -> exact 20-bit prefix P ----
    if (t < 64) {
        uint32_t k2 = KMAX - s_below;             // >= 1
        uint32_t s4 = s_h2[4*t] + s_h2[4*t+1] + s_h2[4*t+2] + s_h2[4*t+3];
        s_s4[t] = s4;
        uint32_t pfx = 0;
#pragma unroll
        for (int q = 0; q < 64; ++q) {
            uint32_t c = s_s4[q];
            pfx += (q < t) ? c : 0u;
        }
        if (pfx < k2 && pfx + s4 >= k2) {         // exactly one lane
            uint32_t a = pfx, s2 = (uint32_t)(4*t);
            for (int q2 = 4*t; q2 < 4*t + 4; ++q2) {
                uint32_t c = s_h2[q2];
                if (a + c >= k2) { s2 = (uint32_t)q2; break; }
                a += c;
            }
            s_sel = (sel1 << 8) | s2;
        }
    }
    __syncthreads();                                          // #6
    const uint32_t P = s_sel;

    // ---- B1: count candidates per bucket ----
#pragma unroll
    for (int q = 0; q < PERTHR; ++q) {
        if ((bits[q] >> 12) <= P + 1)
            atomicAdd(&s_bcnt[bucket_of(bits[q] >> 20, sel1)], 1u);
    }
    __syncthreads();                                          // #7

    // ---- B2: 64-lane broadcast prefix over buckets ----
    if (t < NBKT) {
        uint32_t pfx = 0;
#pragma unroll
        for (int q = 0; q < NBKT; ++q) {
            uint32_t c = s_bcnt[q];
            pfx += (q < t) ? c : 0u;
        }
        s_pfx[t] = pfx;
        s_cur[t] = pfx;
        if (t == NBKT - 1) s_M = pfx + s_bcnt[NBKT - 1];
    }
    __syncthreads();                                          // #8

    // ---- B3: cursor-claim scatter into contiguous buckets ----
#pragma unroll
    for (int q = 0; q < PERTHR; ++q) {
        if ((bits[q] >> 12) <= P + 1) {
            uint32_t bk = bucket_of(bits[q] >> 20, sel1);
            uint32_t s = atomicAdd(&s_cur[bk], 1u);
            if (s < SORT_N) {
                int j = q * NTHR + t;
                s_ktmp[s] = ((u64)bits[q] << 32) | (uint32_t)j;
            }
        }
    }
    __syncthreads();                                          // #9
    const int M = (int)((s_M < (uint32_t)SORT_N) ? s_M : (uint32_t)SORT_N);
    const int T = (M < NFEAT) ? M : NFEAT;

    // ---- B4: rank within own bucket (dense reads); write sorted (distinct array, no barrier) ----
#pragma unroll
    for (int e = 0; e < 2; ++e) {
        int s = t + e * NTHR;
        if (s < M) {
            u64 kk = s_ktmp[s];
            uint32_t bk = bucket_of((uint32_t)(kk >> 52), sel1);
            int lo = (int)s_pfx[bk];
            int hi = lo + (int)s_bcnt[bk];
            if (hi > M) hi = M;
            int cnt = 0;
            for (int r = lo; r < hi; ++r)
                cnt += (s_ktmp[r] < kk);
            int rank = lo + cnt;
            if (rank < SORT_N) s_ksort[rank] = kk;
        }
    }
    __syncthreads();                                          // #10

    // ---- C1: PPF features dense by rank (thread t -> ranks t, t+256) ----
    const float inv_pi = 0.31830988618379067154f;
#pragma unroll
    for (int e = 0; e < 2; ++e) {
        int r = t + e * NTHR;
        if (r < T) {
            u64 kk = s_ksort[r];
            int j = (int)(uint32_t)(kk & 0xFFFFFFFFull);
            float xj = ptsB[3*j], yj = ptsB[3*j+1], zj = ptsB[3*j+2];
            float mx = nrmB[3*j], my = nrmB[3*j+1], mz = nrmB[3*j+2];
            float dx = xj - pix, dy = yj - piy, dz = zj - piz;
            float d = sqrtf(dx*dx + dy*dy + dz*dz);

            float y1 = nix*dx + niy*dy + niz*dz;
            float c1x = niy*dz - niz*dy, c1y = niz*dx - nix*dz, c1z = nix*dy - niy*dx;
            float x1 = sqrtf(c1x*c1x + c1y*c1y + c1z*c1z);
            float a1 = atan2f(x1, y1) * inv_pi;

            float y2 = mx*dx + my*dy + mz*dz;
            float c2x = my*dz - mz*dy, c2y = mz*dx - mx*dz, c2z = mx*dy - my*dx;
            float x2 = sqrtf(c2x*c2x + c2y*c2y + c2z*c2z);
            float a2 = atan2f(x2, y2) * inv_pi;

            float y3 = nix*mx + niy*my + niz*mz;
            float c3x = niy*mz - niz*my, c3y = niz*mx - nix*mz, c3z = nix*my - niy*mx;
            float x3 = sqrtf(c3x*c3x + c3y*c3y + c3z*c3z);
            float a3 = atan2f(x3, y3) * inv_pi;

            // self-point: reference reductions init accumulator with +0.0 ->
            // y = +0 regardless of signed-zero products -> arctan2(+0,+0)=0.
            if (j == i) { d = 0.0f; a1 = 0.0f; a2 = 0.0f; }

            s_feat[r][0] = d; s_feat[r][1] = a1; s_feat[r][2] = a2; s_feat[r][3] = a3;
        }
    }
    __syncthreads();                                          // #11

    // ---- C2: band means with tie-run smoothing at boundaries (identical to R13) ----
    if (t < 24) {
        const int band = t >> 2, f = t & 3;
        const int lo = (band == 0) ? 0 : (10 << (band - 1));
        const int hi = (band == 5) ? 300 : (10 << band);

        float sum = 0.f;
        int mid_lo = lo;
        int mid_hi = (hi < T) ? hi : T;

        #define BITS(r) ((uint32_t)(s_ksort[(r)] >> 32))
        #define CHAINED(r) (BITS(r) - BITS((r)-1) <= TIE_TOL)

        if (lo > 0 && lo < T && CHAINED(lo)) {
            int a = lo - 1; while (a > 0 && CHAINED(a)) --a;
            int bq = lo;    while (bq + 1 < T && CHAINED(bq + 1)) ++bq;
            float w = (float)(bq + 1 - lo) / (float)(bq + 1 - a);
            for (int r = a; r <= bq; ++r) sum += w * s_feat[r][f];
            mid_lo = bq + 1;
        }
        if (hi < T && CHAINED(hi)) {
            int a = hi - 1; while (a > 0 && CHAINED(a)) --a;
            int bq = hi;    while (bq + 1 < T && CHAINED(bq + 1)) ++bq;
            float w = (float)(hi - a) / (float)(bq + 1 - a);
            for (int r = a; r <= bq; ++r) sum += w * s_feat[r][f];
            mid_hi = a;
        }
        #undef BITS
        #undef CHAINED

        for (int r = mid_lo; r < mid_hi; ++r) sum += s_feat[r][f];
        out[(size_t)row * 24 + band * 4 + f] = sum / (float)(hi - lo);
    }
}

extern "C" void kernel_launch(void* const* d_in, const int* in_sizes, int n_in,
                              void* d_out, int out_size, void* d_ws, size_t ws_size,
                              hipStream_t stream) {
    (void)n_in; (void)out_size; (void)d_ws; (void)ws_size;
    const float* pts = (const float*)d_in[0];
    const float* nrm = (const float*)d_in[1];
    float* out = (float*)d_out;
    const int rows = in_sizes[0] / 3;   // b * n = 32768
    ppf_kernel<<<dim3(rows), dim3(NTHR), 0, stream>>>(pts, nrm, out);
}

// Round 15
// 337.914 us; speedup vs baseline: 8.5118x; 1.0209x over previous
//
#include <hip/hip_runtime.h>
#include <math.h>
#include <stdint.h>

#define NPTS 4096
#define KMAX 300
#define SORT_N 512
#define NTHR 256
#define PERTHR 16            // NPTS / NTHR
#define NFEAT 336            // features kept for ranks < NFEAT
#define TIE_TOL 4u           // full-bits ulp window: "reference order unknowable"
#define NBIN 4096            // stage-1 histogram on bits>>20
#define NBKT 64              // rank buckets anchored at the cut

typedef unsigned long long u64;

__device__ __forceinline__ uint32_t bucket_of(uint32_t code12, uint32_t sel1) {
    uint32_t d = (code12 >= sel1) ? 0u : (sel1 - code12);
    if (d > NBKT - 1) d = NBKT - 1;
    return (uint32_t)(NBKT - 1) - d;     // monotone nondecreasing in code12
}

__global__ __launch_bounds__(NTHR) void ppf_kernel(
    const float* __restrict__ pts,
    const float* __restrict__ nrm,
    float* __restrict__ out)
{
    const int row = blockIdx.x;          // b*4096 + i
    const int b = row >> 12;
    const int i = row & (NPTS - 1);
    const int t = threadIdx.x;

    // s_buf (16 KB) phases:
    //  A: uint32 hist[4096] (16 KB)
    //  B/C: ktmp u64[512] @0 | ksort u64[512] @4K | feat[336][4] @8K (5.25 KB)
    __shared__ __align__(16) unsigned char s_buf[NBIN * 4];
    uint32_t* s_hist = (uint32_t*)s_buf;
    u64* s_ktmp = (u64*)s_buf;
    u64* s_ksort = (u64*)(s_buf + 4096);
    float (*s_feat)[4] = (float(*)[4])(s_buf + 8192);
    __shared__ uint32_t s_gsum[NTHR];    // stage-1 16-bin group sums
    __shared__ uint32_t s_h2[NTHR];      // stage-2 256-bin hist
    __shared__ uint32_t s_s4[64];        // wave-0 4-group partial sums
    __shared__ uint32_t s_bcnt[NBKT];
    __shared__ uint32_t s_pfx[NBKT];
    __shared__ uint32_t s_cur[NBKT];
    __shared__ uint32_t s_sel;           // stage1: sel1; stage2: 20-bit prefix P
    __shared__ uint32_t s_below;
    __shared__ uint32_t s_M;

    const float* ptsB = pts + (size_t)b * NPTS * 3;
    const float* nrmB = nrm + (size_t)b * NPTS * 3;

    const float pix = ptsB[3*i], piy = ptsB[3*i+1], piz = ptsB[3*i+2];
    const float nix = nrmB[3*i], niy = nrmB[3*i+1], niz = nrmB[3*i+2];
    float sqi;
    {
#pragma clang fp contract(off)
        sqi = pix*pix + piy*piy + piz*piz;
    }

    // ---- A0: zero stage-1 histogram (vectorized) ----
    {
        uint4* H4 = (uint4*)s_hist;
#pragma unroll
        for (int q = 0; q < 4; ++q) H4[q * NTHR + t] = make_uint4(0u, 0u, 0u, 0u);
    }
    __syncthreads();                                          // #1

    // ---- A1: d2 bits for OWN CONTIGUOUS 16 points (float4 loads, immediate offsets).
    //      Thread t owns points j = 16t + q. d2 arithmetic bit-identical to R14;
    //      only the load path differs. Sort (B4) erases the order change. ----
    uint32_t bits[PERTHR];
    {
        const float4* P4 = (const float4*)(ptsB) + t * 12;    // 48 floats/thread
#pragma unroll
        for (int c = 0; c < 4; ++c) {
            float4 v0 = P4[c*3 + 0];
            float4 v1 = P4[c*3 + 1];
            float4 v2 = P4[c*3 + 2];
            float px[4], py[4], pz[4];
            px[0] = v0.x; py[0] = v0.y; pz[0] = v0.z;
            px[1] = v0.w; py[1] = v1.x; pz[1] = v1.y;
            px[2] = v1.z; py[2] = v1.w; pz[2] = v2.x;
            px[3] = v2.y; py[3] = v2.z; pz[3] = v2.w;
#pragma unroll
            for (int u = 0; u < 4; ++u) {
#pragma clang fp contract(off)
                float xj = px[u], yj = py[u], zj = pz[u];
                float sqj = xj*xj + yj*yj + zj*zj;
                float dot = pix*xj + piy*yj + piz*zj;
                float d2 = sqi + sqj - 2.0f*dot;
                d2 = fmaxf(d2, 0.0f);
                bits[c*4 + u] = __float_as_uint(d2);
            }
        }
    }
#pragma unroll
    for (int q = 0; q < PERTHR; ++q)
        atomicAdd(&s_hist[bits[q] >> 20], 1u);
    __syncthreads();                                          // #2

    // ---- A2: per-thread 16-bin group sums (vectorized); zero stage-2 + buckets ----
    {
        const uint4* H4 = (const uint4*)s_hist;
        uint32_t gs = 0;
#pragma unroll
        for (int q = 0; q < 4; ++q) {
            uint4 v = H4[t*4 + q];
            gs += v.x + v.y + v.z + v.w;
        }
        s_gsum[t] = gs;
    }
    s_h2[t] = 0;
    if (t < NBKT) s_bcnt[t] = 0;
    __syncthreads();                                          // #3

    // ---- A3 (wave 0): in-wave broadcast prefix; cut-owning lane refines sel1/below ----
    if (t < 64) {
        uint32_t s4 = s_gsum[4*t] + s_gsum[4*t+1] + s_gsum[4*t+2] + s_gsum[4*t+3];
        s_s4[t] = s4;
        uint32_t pfx = 0;
#pragma unroll
        for (int q = 0; q < 64; ++q) {
            uint32_t c = s_s4[q];                 // broadcast read, in-wave ordered
            pfx += (q < t) ? c : 0u;
        }
        if (pfx < KMAX && pfx + s4 >= KMAX) {     // exactly one lane
            uint32_t a = pfx, selbin = 0, below = 0;
            for (int g = 4*t; g < 4*t + 4; ++g) {
                uint32_t gs = s_gsum[g];
                if (a + gs >= KMAX) {
                    for (int q = 0; q < 16; ++q) {
                        uint32_t c = s_hist[g*16 + q];
                        if (a + c >= KMAX) { selbin = (uint32_t)(g*16 + q); below = a; break; }
                        a += c;
                    }
                    break;
                }
                a += gs;
            }
            s_sel = selbin;
            s_below = below;
        }
    }
    __syncthreads();                                          // #4
    const uint32_t sel1 = s_sel;

    // ---- A4: stage-2 hist (256 bins on bits[19:12], restricted to bin sel1) ----
#pragma unroll
    for (int q = 0; q < PERTHR; ++q) {
        if ((bits[q] >> 20) == sel1)
            atomicAdd(&s_h2[(bits[q] >> 12) & 255u], 1u);
    }
    __syncthreads();                                          // #5

    // ---- A5 (wave 0): parallel scan of stage-2 hist -> exact 20-bit prefix P ----
    if (t < 64) {
        uint32_t k2 = KMAX - s_below;             // >= 1
        uint32_t s4 = s_h2[4*t] + s_h2[4*t+1] + s_h2[4*t+2] + s_h2[4*t+3];
        s_s4[t] = s4;
        uint32_t pfx = 0;
#pragma unroll
        for (int q = 0; q < 64; ++q) {
            uint32_t c = s_s4[q];
            pfx += (q < t) ? c : 0u;
        }
        if (pfx < k2 && pfx + s4 >= k2) {         // exactly one lane
            uint32_t a = pfx, s2 = (uint32_t)(4*t);
            for (int q2 = 4*t; q2 < 4*t + 4; ++q2) {
                uint32_t c = s_h2[q2];
                if (a + c >= k2) { s2 = (uint32_t)q2; break; }
                a += c;
            }
            s_sel = (sel1 << 8) | s2;
        }
    }
    __syncthreads();                                          // #6
    const uint32_t P = s_sel;

    // ---- B1: count candidates per bucket ----
#pragma unroll
    for (int q = 0; q < PERTHR; ++q) {
        if ((bits[q] >> 12) <= P + 1)
            atomicAdd(&s_bcnt[bucket_of(bits[q] >> 20, sel1)], 1u);
    }
    __syncthreads();                                          // #7

    // ---- B2: 64-lane broadcast prefix over buckets ----
    if (t < NBKT) {
        uint32_t pfx = 0;
#pragma unroll
        for (int q = 0; q < NBKT; ++q) {
            uint32_t c = s_bcnt[q];
            pfx += (q < t) ? c : 0u;
        }
        s_pfx[t] = pfx;
        s_cur[t] = pfx;
        if (t == NBKT - 1) s_M = pfx + s_bcnt[NBKT - 1];
    }
    __syncthreads();                                          // #8

    // ---- B3: cursor-claim scatter into contiguous buckets ----
#pragma unroll
    for (int q = 0; q < PERTHR; ++q) {
        if ((bits[q] >> 12) <= P + 1) {
            uint32_t bk = bucket_of(bits[q] >> 20, sel1);
            uint32_t s = atomicAdd(&s_cur[bk], 1u);
            if (s < SORT_N) {
                int j = t * PERTHR + q;           // contiguous mapping
                s_ktmp[s] = ((u64)bits[q] << 32) | (uint32_t)j;
            }
        }
    }
    __syncthreads();                                          // #9
    const int M = (int)((s_M < (uint32_t)SORT_N) ? s_M : (uint32_t)SORT_N);
    const int T = (M < NFEAT) ? M : NFEAT;

    // ---- B4: rank within own bucket (dense reads); write sorted (distinct array) ----
#pragma unroll
    for (int e = 0; e < 2; ++e) {
        int s = t + e * NTHR;
        if (s < M) {
            u64 kk = s_ktmp[s];
            uint32_t bk = bucket_of((uint32_t)(kk >> 52), sel1);
            int lo = (int)s_pfx[bk];
            int hi = lo + (int)s_bcnt[bk];
            if (hi > M) hi = M;
            int cnt = 0;
            for (int r = lo; r < hi; ++r)
                cnt += (s_ktmp[r] < kk);
            int rank = lo + cnt;
            if (rank < SORT_N) s_ksort[rank] = kk;
        }
    }
    __syncthreads();                                          // #10

    // ---- C1: PPF features dense by rank (thread t -> ranks t, t+256) ----
    const float inv_pi = 0.31830988618379067154f;
#pragma unroll
    for (int e = 0; e < 2; ++e) {
        int r = t + e * NTHR;
        if (r < T) {
            u64 kk = s_ksort[r];
            int j = (int)(uint32_t)(kk & 0xFFFFFFFFull);
            float xj = ptsB[3*j], yj = ptsB[3*j+1], zj = ptsB[3*j+2];
            float mx = nrmB[3*j], my = nrmB[3*j+1], mz = nrmB[3*j+2];
            float dx = xj - pix, dy = yj - piy, dz = zj - piz;
            float d = sqrtf(dx*dx + dy*dy + dz*dz);

            float y1 = nix*dx + niy*dy + niz*dz;
            float c1x = niy*dz - niz*dy, c1y = niz*dx - nix*dz, c1z = nix*dy - niy*dx;
            float x1 = sqrtf(c1x*c1x + c1y*c1y + c1z*c1z);
            float a1 = atan2f(x1, y1) * inv_pi;

            float y2 = mx*dx + my*dy + mz*dz;
            float c2x = my*dz - mz*dy, c2y = mz*dx - mx*dz, c2z = mx*dy - my*dx;
            float x2 = sqrtf(c2x*c2x + c2y*c2y + c2z*c2z);
            float a2 = atan2f(x2, y2) * inv_pi;

            float y3 = nix*mx + niy*my + niz*mz;
            float c3x = niy*mz - niz*my, c3y = niz*mx - nix*mz, c3z = nix*my - niy*mx;
            float x3 = sqrtf(c3x*c3x + c3y*c3y + c3z*c3z);
            float a3 = atan2f(x3, y3) * inv_pi;

            // self-point: reference reductions init accumulator with +0.0 ->
            // y = +0 regardless of signed-zero products -> arctan2(+0,+0)=0.
            if (j == i) { d = 0.0f; a1 = 0.0f; a2 = 0.0f; }

            s_feat[r][0] = d; s_feat[r][1] = a1; s_feat[r][2] = a2; s_feat[r][3] = a3;
        }
    }
    __syncthreads();                                          // #11

    // ---- C2: band means with tie-run smoothing at boundaries (identical to R14) ----
    if (t < 24) {
        const int band = t >> 2, f = t & 3;
        const int lo = (band == 0) ? 0 : (10 << (band - 1));
        const int hi = (band == 5) ? 300 : (10 << band);

        float sum = 0.f;
        int mid_lo = lo;
        int mid_hi = (hi < T) ? hi : T;

        #define BITS(r) ((uint32_t)(s_ksort[(r)] >> 32))
        #define CHAINED(r) (BITS(r) - BITS((r)-1) <= TIE_TOL)

        if (lo > 0 && lo < T && CHAINED(lo)) {
            int a = lo - 1; while (a > 0 && CHAINED(a)) --a;
            int bq = lo;    while (bq + 1 < T && CHAINED(bq + 1)) ++bq;
            float w = (float)(bq + 1 - lo) / (float)(bq + 1 - a);
            for (int r = a; r <= bq; ++r) sum += w * s_feat[r][f];
            mid_lo = bq + 1;
        }
        if (hi < T && CHAINED(hi)) {
            int a = hi - 1; while (a > 0 && CHAINED(a)) --a;
            int bq = hi;    while (bq + 1 < T && CHAINED(bq + 1)) ++bq;
            float w = (float)(hi - a) / (float)(bq + 1 - a);
            for (int r = a; r <= bq; ++r) sum += w * s_feat[r][f];
            mid_hi = a;
        }
        #undef BITS
        #undef CHAINED

        for (int r = mid_lo; r < mid_hi; ++r) sum += s_feat[r][f];
        out[(size_t)row * 24 + band * 4 + f] = sum / (float)(hi - lo);
    }
}

extern "C" void kernel_launch(void* const* d_in, const int* in_sizes, int n_in,
                              void* d_out, int out_size, void* d_ws, size_t ws_size,
                              hipStream_t stream) {
    (void)n_in; (void)out_size; (void)d_ws; (void)ws_size;
    const float* pts = (const float*)d_in[0];
    const float* nrm = (const float*)d_in[1];
    float* out = (float*)d_out;
    const int rows = in_sizes[0] / 3;   // b * n = 32768
    ppf_kernel<<<dim3(rows), dim3(NTHR), 0, stream>>>(pts, nrm, out);
}